// Round 3
// baseline (247.445 us; speedup 1.0000x reference)
//
#include <hip/hip_runtime.h>

#define CHANNELS 3
#define HW 512
#define KS 15
#define GPAD 7
#define TILE 64
#define HT (TILE + 2 * GPAD)   // 78 mid rows
#define MID_STR (TILE + 1)     // 65: consecutive rows -> consecutive banks; col walks free
#define WIN (16 + KS - 1)      // 30-tap window per 16-output chunk

// Accumulate one input element (window index J) into the 16 sliding-window outputs.
template<int J>
__device__ __forceinline__ void acc_tap(float (&acc)[16], const float (&w)[KS], float v) {
    if constexpr (J >= 0 && J < WIN) {
        constexpr int lo = (J - (KS - 1)) > 0 ? (J - (KS - 1)) : 0;
        constexpr int hi = (J < 15) ? J : 15;
        #pragma unroll
        for (int o = lo; o <= hi; ++o) acc[o] = fmaf(w[J - o], v, acc[o]);
    }
}

// One float4 of the aligned 32-float window; element m = 4Q+e maps to J = m-1
// (the aligned window starts one float before the first needed input).
template<int Q>
__device__ __forceinline__ void acc_quad(float (&acc)[16], const float (&w)[KS], float4 v) {
    acc_tap<4 * Q - 1>(acc, w, v.x);
    acc_tap<4 * Q + 0>(acc, w, v.y);
    acc_tap<4 * Q + 1>(acc, w, v.z);
    acc_tap<4 * Q + 2>(acc, w, v.w);
}

__global__ __launch_bounds__(256, 8)   // VGPR<=64 for 8 waves/SIMD; LDS 20KiB -> 8 blocks/CU
void gauss_blur_kernel(const float* __restrict__ x,
                       const float* __restrict__ sigma,
                       float* __restrict__ out) {
    __shared__ float mid_s[HT * MID_STR];  // 78 x 65 floats = 20280 B

    const int tid   = threadIdx.x;   // 0..255
    const int tileX = blockIdx.x;    // 0..7
    const int tileY = blockIdx.y;    // 0..7
    const int bc    = blockIdx.z;    // 0..B*C-1
    const int b     = bc / CHANNELS;

    // per-batch 1D Gaussian weights (separable; S^2+1e-8 vs (S1)^2 diff <= 1e-8 rel)
    float w[KS];
    {
        const float s = sigma[b];
        const float inv_denom = 1.0f / (2.0f * s * s + 1e-8f);
        float sum = 0.0f;
        #pragma unroll
        for (int i = 0; i < KS; ++i) {
            const float d = (float)(i - GPAD);
            const float g = __expf(-d * d * inv_denom);
            w[i] = g;
            sum += g;
        }
        const float inv = 1.0f / sum;
        #pragma unroll
        for (int i = 0; i < KS; ++i) w[i] *= inv;
    }

    const size_t plane = (size_t)HW * HW;
    const float* xp = x + (size_t)bc * plane;
    float* op       = out + (size_t)bc * plane;
    const int gy0 = tileY * TILE - GPAD;

    // ---- stage A: horizontal pass, straight from global (no input staging).
    // 78 rows x 4 chunks of 16 outputs. Aligned window: floats [cc0-8, cc0+24). ----
    for (int i = tid; i < HT * 4; i += 256) {
        const int r  = i >> 2;
        const int ch = i & 3;
        float acc[16];
        #pragma unroll
        for (int o = 0; o < 16; ++o) acc[o] = 0.0f;

        const int gy = gy0 + r;
        if ((unsigned)gy < (unsigned)HW) {
            const float* rowp = xp + (size_t)gy * HW;
            const int cc0 = tileX * TILE + ch * 16;  // global col of this chunk's output 0
            const int a0  = cc0 - 8;                 // 16B-aligned window start
            if (a0 >= 0 && a0 + 32 <= HW) {
                const float4* v4 = (const float4*)(rowp + a0);
                acc_quad<0>(acc, w, v4[0]);
                acc_quad<1>(acc, w, v4[1]);
                acc_quad<2>(acc, w, v4[2]);
                acc_quad<3>(acc, w, v4[3]);
                acc_quad<4>(acc, w, v4[4]);
                acc_quad<5>(acc, w, v4[5]);
                acc_quad<6>(acc, w, v4[6]);
                acc_quad<7>(acc, w, v4[7]);
            } else {
                // image edge: scalar loads with per-column zero padding
                #pragma unroll
                for (int j = 0; j < WIN; ++j) {
                    const int col = cc0 - GPAD + j;
                    float v = 0.0f;
                    if ((unsigned)col < (unsigned)HW) v = rowp[col];
                    const int lo = (j - (KS - 1)) > 0 ? (j - (KS - 1)) : 0;
                    const int hi = (j < 15) ? j : 15;
                    #pragma unroll
                    for (int o = lo; o <= hi; ++o) acc[o] = fmaf(w[j - o], v, acc[o]);
                }
            }
        }
        float* dst = &mid_s[r * MID_STR + ch * 16];
        #pragma unroll
        for (int o = 0; o < 16; ++o) dst[o] = acc[o];  // <=2-way bank aliasing: free
    }
    __syncthreads();

    // ---- stage B: vertical pass from LDS; nontemporal streaming stores to out
    // (output has zero reuse -> keep it out of L2 dirty residency). ----
    {
        const int c  = tid & (TILE - 1);
        const int r0 = (tid >> 6) * 16;
        float acc[16];
        #pragma unroll
        for (int o = 0; o < 16; ++o) acc[o] = 0.0f;
        #pragma unroll
        for (int j = 0; j < WIN; ++j) {
            const float v = mid_s[(r0 + j) * MID_STR + c];
            const int lo = (j - (KS - 1)) > 0 ? (j - (KS - 1)) : 0;
            const int hi = (j < 15) ? j : 15;
            #pragma unroll
            for (int o = lo; o <= hi; ++o) acc[o] = fmaf(w[j - o], v, acc[o]);
        }
        const int gx = tileX * TILE + c;
        #pragma unroll
        for (int o = 0; o < 16; ++o)
            __builtin_nontemporal_store(acc[o],
                &op[(size_t)(tileY * TILE + r0 + o) * HW + gx]);
    }
}

extern "C" void kernel_launch(void* const* d_in, const int* in_sizes, int n_in,
                              void* d_out, int out_size, void* d_ws, size_t ws_size,
                              hipStream_t stream) {
    const float* x     = (const float*)d_in[0];
    const float* sigma = (const float*)d_in[1];
    float* out         = (float*)d_out;
    const int B = in_sizes[1];  // 32
    dim3 grid(HW / TILE, HW / TILE, B * CHANNELS);
    gauss_blur_kernel<<<grid, dim3(256, 1, 1), 0, stream>>>(x, sigma, out);
}

// Round 4
// 190.388 us; speedup vs baseline: 1.2997x; 1.2997x over previous
//
#include <hip/hip_runtime.h>

#define CHANNELS 3
#define HW 512
#define KS 15
#define GPAD 7
#define TILE 64
#define HT (TILE + 2 * GPAD)   // 78 tile rows (with halo)
#define IN_STR 81              // odd stride: all LDS phases <=2-way bank aliasing (free)
#define WCOLS 20               // 20 float4 = 80 staged cols [gx0-8, gx0+72)
#define WIN (16 + KS - 1)      // 30-tap window per 16-output chunk

__global__ __launch_bounds__(256, 6)   // LDS 25.3KiB -> 6 blocks/CU; VGPR ~60 fits 6 waves/SIMD
void gauss_blur_kernel(const float* __restrict__ x,
                       const float* __restrict__ sigma,
                       float* __restrict__ out) {
    // Single LDS buffer, reused in place:
    //   phase 0: input tile rows [gy0, gy0+78) x cols [gx0-8, gx0+72)  (78 x 80)
    //   phase 2: horizontal-pass result (mid) overwrites cols [0, 64)  (78 x 64)
    __shared__ float in_s[HT * IN_STR];   // 78 x 81 floats = 25272 B

    const int tid   = threadIdx.x;   // 0..255
    const int tileX = blockIdx.x;    // 0..7
    const int tileY = blockIdx.y;    // 0..7
    const int bc    = blockIdx.z;    // 0..B*C-1
    const int b     = bc / CHANNELS;

    // per-batch 1D Gaussian weights (separable; S^2+1e-8 vs (S1)^2 diff <= 1e-8 rel)
    float w[KS];
    {
        const float s = sigma[b];
        const float inv_denom = 1.0f / (2.0f * s * s + 1e-8f);
        float sum = 0.0f;
        #pragma unroll
        for (int i = 0; i < KS; ++i) {
            const float d = (float)(i - GPAD);
            const float g = __expf(-d * d * inv_denom);
            w[i] = g;
            sum += g;
        }
        const float inv = 1.0f / sum;
        #pragma unroll
        for (int i = 0; i < KS; ++i) w[i] *= inv;
    }

    const size_t plane = (size_t)HW * HW;
    const float* xp = x + (size_t)bc * plane;
    float* op       = out + (size_t)bc * plane;
    const int gx0 = tileX * TILE;          // first output col of tile
    const int gy0 = tileY * TILE - GPAD;   // first staged row
    const int ax0 = gx0 - 8;               // 32B-aligned staged-window start col

    // ---- phase 0: stage input tile global -> LDS, float4, one-touch reads.
    // 78 rows x 20 float4; zero-pad out-of-image. ----
    for (int i = tid; i < HT * WCOLS; i += 256) {
        const int r = i / WCOLS;
        const int q = i - r * WCOLS;
        const int gy = gy0 + r;
        const int gc = ax0 + 4 * q;
        float4 v = make_float4(0.f, 0.f, 0.f, 0.f);
        if ((unsigned)gy < (unsigned)HW) {
            const float* rowp = xp + (size_t)gy * HW;
            if (gc >= 0 && gc + 4 <= HW) {
                v = *(const float4*)(rowp + gc);
            } else {
                if ((unsigned)(gc + 0) < (unsigned)HW) v.x = rowp[gc + 0];
                if ((unsigned)(gc + 1) < (unsigned)HW) v.y = rowp[gc + 1];
                if ((unsigned)(gc + 2) < (unsigned)HW) v.z = rowp[gc + 2];
                if ((unsigned)(gc + 3) < (unsigned)HW) v.w = rowp[gc + 3];
            }
        }
        float* d = &in_s[r * IN_STR + 4 * q];
        d[0] = v.x; d[1] = v.y; d[2] = v.z; d[3] = v.w;
    }
    __syncthreads();

    // ---- phase 1: horizontal pass, LDS -> registers (accumulate on load).
    // Work item i -> (row i>>2, chunk i&3); thread does items tid and tid+256.
    // Output local col oc = 16*ch + o reads staged cols [oc+1, oc+30) (LDS
    // col = global col - ax0, so -7 offset becomes +1). ----
    float acc[2][16];
    #pragma unroll
    for (int p = 0; p < 2; ++p)
        #pragma unroll
        for (int o = 0; o < 16; ++o) acc[p][o] = 0.0f;

    #pragma unroll
    for (int p = 0; p < 2; ++p) {
        const int i = tid + p * 256;
        if (i < HT * 4) {
            const int r  = i >> 2;
            const int ch = i & 3;
            const float* src = &in_s[r * IN_STR + 16 * ch + 1];
            #pragma unroll
            for (int j = 0; j < WIN; ++j) {
                const float v = src[j];
                const int lo = (j - (KS - 1)) > 0 ? (j - (KS - 1)) : 0;
                const int hi = (j < 15) ? j : 15;
                #pragma unroll
                for (int o = lo; o <= hi; ++o)
                    acc[p][o] = fmaf(w[j - o], v, acc[p][o]);
            }
        }
    }
    __syncthreads();   // all LDS reads done before in-place overwrite

    // ---- phase 2: write mid back into the same LDS buffer (cols 0..63) ----
    #pragma unroll
    for (int p = 0; p < 2; ++p) {
        const int i = tid + p * 256;
        if (i < HT * 4) {
            const int r  = i >> 2;
            const int ch = i & 3;
            float* dst = &in_s[r * IN_STR + 16 * ch];
            #pragma unroll
            for (int o = 0; o < 16; ++o) dst[o] = acc[p][o];
        }
    }
    __syncthreads();

    // ---- phase 3: vertical pass from LDS, accumulate on load; coalesced
    // 256B/wave stores (regular — nt regressed in round 3). ----
    {
        const int c  = tid & (TILE - 1);
        const int r0 = (tid >> 6) * 16;
        float vacc[16];
        #pragma unroll
        for (int o = 0; o < 16; ++o) vacc[o] = 0.0f;
        #pragma unroll
        for (int j = 0; j < WIN; ++j) {
            const float v = in_s[(r0 + j) * IN_STR + c];
            const int lo = (j - (KS - 1)) > 0 ? (j - (KS - 1)) : 0;
            const int hi = (j < 15) ? j : 15;
            #pragma unroll
            for (int o = lo; o <= hi; ++o) vacc[o] = fmaf(w[j - o], v, vacc[o]);
        }
        const int gx = gx0 + c;
        #pragma unroll
        for (int o = 0; o < 16; ++o)
            op[(size_t)(tileY * TILE + r0 + o) * HW + gx] = vacc[o];
    }
}

extern "C" void kernel_launch(void* const* d_in, const int* in_sizes, int n_in,
                              void* d_out, int out_size, void* d_ws, size_t ws_size,
                              hipStream_t stream) {
    const float* x     = (const float*)d_in[0];
    const float* sigma = (const float*)d_in[1];
    float* out         = (float*)d_out;
    const int B = in_sizes[1];  // 32
    dim3 grid(HW / TILE, HW / TILE, B * CHANNELS);
    gauss_blur_kernel<<<grid, dim3(256, 1, 1), 0, stream>>>(x, sigma, out);
}